// Round 1
// baseline (501.941 us; speedup 1.0000x reference)
//
#include <hip/hip_runtime.h>
#include <math.h>

#define NN 3072
#define PP 4
#define INF_ 256
#define FF 64
#define LEAK 0.2f

// workspace layout (float offsets)
#define WH_OFF   0                        // N*F = 196608
#define WH1_OFF  (NN * FF)                // 196608
#define WH2_OFF  (WH1_OFF + NN)           // 199680
#define RS_OFF   (WH2_OFF + NN)           // 202752
#define CS_OFF   (RS_OFF + PP * NN)       // 215040  (atomic accum, must be zeroed)
#define U_OFF    (CS_OFF + PP * NN)       // 227328
#define V_OFF    (U_OFF + PP * NN)        // 239616
#define SCAL_OFF (V_OFF + PP * NN)        // 251904  (inv_lamb per p)

// K1: Wh = h @ W  [3072,256]x[256,64]; Wh1 = Wh@a[:64]; Wh2 = Wh@a[64:]
__global__ __launch_bounds__(64) void k1_gemm(const float* __restrict__ h,
                                              const float* __restrict__ W,
                                              const float* __restrict__ a,
                                              float* __restrict__ ws) {
    int row = blockIdx.x;
    int f = threadIdx.x;
    __shared__ float hrow[INF_];
    ((float4*)hrow)[f] = ((const float4*)(h + (size_t)row * INF_))[f];
    __syncthreads();
    float acc = 0.f;
#pragma unroll 8
    for (int k = 0; k < INF_; ++k) acc = fmaf(hrow[k], W[k * FF + f], acc);
    ws[WH_OFF + row * FF + f] = acc;
    float s1 = acc * a[f];
    float s2 = acc * a[FF + f];
#pragma unroll
    for (int off = 32; off > 0; off >>= 1) {
        s1 += __shfl_down(s1, off);
        s2 += __shfl_down(s2, off);
    }
    if (f == 0) { ws[WH1_OFF + row] = s1; ws[WH2_OFF + row] = s2; }
}

// K2: e = leaky(Wh1[i]+Wh2[j]) * edge_attr; write e (output 1); rs direct, cs atomics.
// Block = 256 threads handles 16 rows x 3072 cols of one p-slice.
__global__ __launch_bounds__(256) void k2_e(const float* __restrict__ edge,
                                            float* __restrict__ e_out,
                                            float* __restrict__ ws) {
    int p = blockIdx.y;
    int row0 = blockIdx.x * 16;
    int tid = threadIdx.x;
    const float* Wh1 = ws + WH1_OFF;
    const float4* Wh2v = (const float4*)(ws + WH2_OFF);
    float4 wv[3];
#pragma unroll
    for (int c = 0; c < 3; ++c) wv[c] = Wh2v[c * 256 + tid];
    float colAcc[12];
#pragma unroll
    for (int i = 0; i < 12; ++i) colAcc[i] = 0.f;
    __shared__ float rowpart[16][4];
    const size_t slice = (size_t)p * NN * NN;
    for (int r = 0; r < 16; ++r) {
        int row = row0 + r;
        float w1 = Wh1[row];
        const float4* ein = (const float4*)(edge + slice + (size_t)row * NN);
        float4* eout = (float4*)(e_out + slice + (size_t)row * NN);
        float racc = 0.f;
#pragma unroll
        for (int c = 0; c < 3; ++c) {
            int j4 = c * 256 + tid;
            float4 ea = ein[j4];
            float4 w = wv[c];
            float4 ev;
            float b;
            b = w1 + w.x; b = b > 0.f ? b : LEAK * b; ev.x = b * ea.x;
            b = w1 + w.y; b = b > 0.f ? b : LEAK * b; ev.y = b * ea.y;
            b = w1 + w.z; b = b > 0.f ? b : LEAK * b; ev.z = b * ea.z;
            b = w1 + w.w; b = b > 0.f ? b : LEAK * b; ev.w = b * ea.w;
            eout[j4] = ev;
            colAcc[c * 4 + 0] += ev.x; colAcc[c * 4 + 1] += ev.y;
            colAcc[c * 4 + 2] += ev.z; colAcc[c * 4 + 3] += ev.w;
            racc += (ev.x + ev.y) + (ev.z + ev.w);
        }
#pragma unroll
        for (int off = 32; off > 0; off >>= 1) racc += __shfl_down(racc, off);
        if ((tid & 63) == 0) rowpart[r][tid >> 6] = racc;
    }
    __syncthreads();
    if (tid < 64) {
        float v = rowpart[tid >> 2][tid & 3];
        v += __shfl_down(v, 2);
        v += __shfl_down(v, 1);
        if ((tid & 3) == 0) ws[RS_OFF + p * NN + row0 + (tid >> 2)] = v;
    }
    float* cs = ws + CS_OFF + p * NN;
#pragma unroll
    for (int c = 0; c < 3; ++c) {
        int j = (c * 256 + tid) * 4;
        atomicAdd(&cs[j + 0], colAcc[c * 4 + 0]);
        atomicAdd(&cs[j + 1], colAcc[c * 4 + 1]);
        atomicAdd(&cs[j + 2], colAcc[c * 4 + 2]);
        atomicAdd(&cs[j + 3], colAcc[c * 4 + 3]);
    }
}

// K3: per p scalars.  lamb = max(max rs, max cs); r = N*lamb - T (T = sum rs).
// Analytic: column-0 sum of tt == lamb exactly, so denom = lamb.
// u_i = (lamb-rs_i)/(r*lamb);  v_j = lamb - cs_j;  att = e>0 ? e/lamb + u_i*v_j : e
__global__ __launch_bounds__(256) void k3_scal(float* __restrict__ ws) {
    int p = blockIdx.x;
    int tid = threadIdx.x;
    const float* rs = ws + RS_OFF + p * NN;
    const float* cs = ws + CS_OFF + p * NN;
    float mx = -3.4e38f, sum = 0.f;
    for (int i = tid; i < NN; i += 256) {
        float rv = rs[i], cv = cs[i];
        mx = fmaxf(mx, fmaxf(rv, cv));
        sum += rv;
    }
#pragma unroll
    for (int off = 32; off > 0; off >>= 1) {
        mx = fmaxf(mx, __shfl_down(mx, off));
        sum += __shfl_down(sum, off);
    }
    __shared__ float smx[4], ssum[4];
    __shared__ float s_lamb, s_invlr;
    if ((tid & 63) == 0) { smx[tid >> 6] = mx; ssum[tid >> 6] = sum; }
    __syncthreads();
    if (tid == 0) {
        float lamb = fmaxf(fmaxf(smx[0], smx[1]), fmaxf(smx[2], smx[3]));
        float T = ssum[0] + ssum[1] + ssum[2] + ssum[3];
        float r = (float)NN * lamb - T;
        s_lamb = lamb;
        s_invlr = 1.f / (r * lamb);
        ws[SCAL_OFF + p] = 1.f / lamb;
    }
    __syncthreads();
    float lamb = s_lamb, invlr = s_invlr;
    for (int i = tid; i < NN; i += 256) {
        ws[U_OFF + p * NN + i] = (lamb - rs[i]) * invlr;
        ws[V_OFF + p * NN + i] = lamb - cs[i];
    }
}

// K4: h_prime[p,i,:] = sum_j att(e[p,i,j]) * Wh[j,:];  out0[i, p*64+f] = elu.
// Block = 256 threads = 4 waves; 16 rows per block; wave w owns rows w*4..w*4+3,
// lane = output feature f. Attention tile staged (transformed) into LDS as
// att_t[jj][16 rows] so compute reads are broadcast ds_read_b128.
__global__ __launch_bounds__(256) void k4_out(const float* __restrict__ e_in,
                                              const float* __restrict__ ws,
                                              float* __restrict__ out0) {
    int p = blockIdx.y;
    int row0 = blockIdx.x * 16;
    int tid = threadIdx.x;
    int w = tid >> 6;
    int lane = tid & 63;
    __shared__ float att_t[64][16];
    const float* Wh = ws + WH_OFF;
    const float* u = ws + U_OFF + p * NN;
    const float* v = ws + V_OFF + p * NN;
    float invl = ws[SCAL_OFF + p];
    const float* eslice = e_in + (size_t)p * NN * NN;
    float acc0 = 0.f, acc1 = 0.f, acc2 = 0.f, acc3 = 0.f;
    int sr = tid & 15;   // staging row 0..15
    int sj4 = tid >> 4;  // staging j-group 0..15
    float ur = u[row0 + sr];
    const float4* vrow4 = (const float4*)v;
    const float4* erow4 = (const float4*)(eslice + (size_t)(row0 + sr) * NN);
    for (int jt = 0; jt < NN; jt += 64) {
        float4 ev = erow4[(jt >> 2) + sj4];
        float4 vv = vrow4[(jt >> 2) + sj4];
        float4 at;
        at.x = ev.x > 0.f ? fmaf(ur, vv.x, ev.x * invl) : ev.x;
        at.y = ev.y > 0.f ? fmaf(ur, vv.y, ev.y * invl) : ev.y;
        at.z = ev.z > 0.f ? fmaf(ur, vv.z, ev.z * invl) : ev.z;
        at.w = ev.w > 0.f ? fmaf(ur, vv.w, ev.w * invl) : ev.w;
        att_t[sj4 * 4 + 0][sr] = at.x;
        att_t[sj4 * 4 + 1][sr] = at.y;
        att_t[sj4 * 4 + 2][sr] = at.z;
        att_t[sj4 * 4 + 3][sr] = at.w;
        __syncthreads();
        const float* whp = Wh + (size_t)jt * FF + lane;
#pragma unroll 16
        for (int jj = 0; jj < 64; ++jj) {
            float4 av = *(const float4*)&att_t[jj][w * 4];  // broadcast read
            float whv = whp[jj * FF];
            acc0 = fmaf(av.x, whv, acc0);
            acc1 = fmaf(av.y, whv, acc1);
            acc2 = fmaf(av.z, whv, acc2);
            acc3 = fmaf(av.w, whv, acc3);
        }
        __syncthreads();
    }
    float accs[4] = {acc0, acc1, acc2, acc3};
#pragma unroll
    for (int q = 0; q < 4; ++q) {
        float x = accs[q];
        x = x > 0.f ? x : (expf(x) - 1.0f);  // elu, alpha=1
        out0[(size_t)(row0 + w * 4 + q) * (PP * FF) + p * FF + lane] = x;
    }
}

extern "C" void kernel_launch(void* const* d_in, const int* in_sizes, int n_in,
                              void* d_out, int out_size, void* d_ws, size_t ws_size,
                              hipStream_t stream) {
    const float* h    = (const float*)d_in[0];
    const float* edge = (const float*)d_in[1];
    const float* W    = (const float*)d_in[2];
    const float* a    = (const float*)d_in[3];
    float* out0  = (float*)d_out;                       // [N, P*F] elu output
    float* e_out = out0 + (size_t)NN * PP * FF;         // [P, N, N] e output
    float* ws = (float*)d_ws;

    // cs accumulators must start at zero (ws is poisoned each launch)
    hipMemsetAsync(ws + CS_OFF, 0, PP * NN * sizeof(float), stream);

    k1_gemm<<<NN, 64, 0, stream>>>(h, W, a, ws);
    k2_e<<<dim3(NN / 16, PP), 256, 0, stream>>>(edge, e_out, ws);
    k3_scal<<<PP, 256, 0, stream>>>(ws);
    k4_out<<<dim3(NN / 16, PP), 256, 0, stream>>>(e_out, ws, out0);
}

// Round 2
// 399.441 us; speedup vs baseline: 1.2566x; 1.2566x over previous
//
#include <hip/hip_runtime.h>
#include <math.h>

#define NN 3072
#define PP 4
#define INF_ 256
#define FF 64
#define LEAK 0.2f
#define KB2 96   // k2 blocks per p (32 rows each)

// workspace layout (float offsets)
#define WH1_OFF  0                         // 3072
#define WH2_OFF  (WH1_OFF + NN)            // 3072
#define RS_OFF   (WH2_OFF + NN)            // P*N
#define CS_OFF   (RS_OFF + PP * NN)        // P*N
#define U_OFF    (CS_OFF + PP * NN)        // P*N
#define V_OFF    (U_OFF + PP * NN)         // P*N
#define SCAL_OFF (V_OFF + PP * NN)         // 4 (+pad)
#define WHT_OFF  (SCAL_OFF + 8)            // bf16 WhT [F][N] = N*F shorts = N*F/2 floats
#define CP_OFF   (WHT_OFF + (NN * FF) / 2) // col partials: P*KB2*N floats (~4.7 MB)

typedef short short8 __attribute__((ext_vector_type(8)));
typedef float floatx4 __attribute__((ext_vector_type(4)));

__device__ inline unsigned short f2bf(float x) {
    unsigned u = __float_as_uint(x);
    return (unsigned short)((u + 0x7FFFu + ((u >> 16) & 1u)) >> 16);
}

// K1: Wh = h@W; store WhT bf16 [f][row]; Wh1 = Wh@a[:64]; Wh2 = Wh@a[64:]
__global__ __launch_bounds__(64) void k1_gemm(const float* __restrict__ h,
                                              const float* __restrict__ W,
                                              const float* __restrict__ a,
                                              float* __restrict__ ws) {
    int row = blockIdx.x;
    int f = threadIdx.x;
    __shared__ float hrow[INF_];
    ((float4*)hrow)[f] = ((const float4*)(h + (size_t)row * INF_))[f];
    __syncthreads();
    float acc = 0.f;
#pragma unroll 8
    for (int k = 0; k < INF_; ++k) acc = fmaf(hrow[k], W[k * FF + f], acc);
    unsigned short* whT = (unsigned short*)(ws + WHT_OFF);
    whT[(size_t)f * NN + row] = f2bf(acc);
    float s1 = acc * a[f];
    float s2 = acc * a[FF + f];
#pragma unroll
    for (int off = 32; off > 0; off >>= 1) {
        s1 += __shfl_down(s1, off);
        s2 += __shfl_down(s2, off);
    }
    if (f == 0) { ws[WH1_OFF + row] = s1; ws[WH2_OFF + row] = s2; }
}

// K2: e = leaky(Wh1[i]+Wh2[j])*edge; write e; row sums direct; col partials (NO atomics).
// Block = 256 threads, 32 rows x 3072 cols of one p-slice. Grid (96, P).
__global__ __launch_bounds__(256) void k2_e(const float* __restrict__ edge,
                                            float* __restrict__ e_out,
                                            float* __restrict__ ws) {
    int p = blockIdx.y;
    int row0 = blockIdx.x * 32;
    int tid = threadIdx.x;
    const float* Wh1 = ws + WH1_OFF;
    const float4* Wh2v = (const float4*)(ws + WH2_OFF);
    float4 wv[3];
#pragma unroll
    for (int c = 0; c < 3; ++c) wv[c] = Wh2v[c * 256 + tid];
    float colAcc[12];
#pragma unroll
    for (int i = 0; i < 12; ++i) colAcc[i] = 0.f;
    __shared__ float rowpart[32][4];
    const size_t slice = (size_t)p * NN * NN;
    for (int r = 0; r < 32; ++r) {
        int row = row0 + r;
        float w1 = Wh1[row];
        const float4* ein = (const float4*)(edge + slice + (size_t)row * NN);
        float4* eout = (float4*)(e_out + slice + (size_t)row * NN);
        float racc = 0.f;
#pragma unroll
        for (int c = 0; c < 3; ++c) {
            int j4 = c * 256 + tid;
            float4 ea = ein[j4];
            float4 w = wv[c];
            float4 ev;
            float b;
            b = w1 + w.x; b = b > 0.f ? b : LEAK * b; ev.x = b * ea.x;
            b = w1 + w.y; b = b > 0.f ? b : LEAK * b; ev.y = b * ea.y;
            b = w1 + w.z; b = b > 0.f ? b : LEAK * b; ev.z = b * ea.z;
            b = w1 + w.w; b = b > 0.f ? b : LEAK * b; ev.w = b * ea.w;
            eout[j4] = ev;
            colAcc[c * 4 + 0] += ev.x; colAcc[c * 4 + 1] += ev.y;
            colAcc[c * 4 + 2] += ev.z; colAcc[c * 4 + 3] += ev.w;
            racc += (ev.x + ev.y) + (ev.z + ev.w);
        }
#pragma unroll
        for (int off = 32; off > 0; off >>= 1) racc += __shfl_down(racc, off);
        if ((tid & 63) == 0) rowpart[r][tid >> 6] = racc;
    }
    __syncthreads();
    if (tid < 128) {
        float vv = rowpart[tid >> 2][tid & 3];
        vv += __shfl_down(vv, 2);
        vv += __shfl_down(vv, 1);
        if ((tid & 3) == 0) ws[RS_OFF + p * NN + row0 + (tid >> 2)] = vv;
    }
    float4* cp = (float4*)(ws + CP_OFF + (size_t)(p * KB2 + blockIdx.x) * NN);
#pragma unroll
    for (int c = 0; c < 3; ++c) {
        float4 cv;
        cv.x = colAcc[c * 4 + 0]; cv.y = colAcc[c * 4 + 1];
        cv.z = colAcc[c * 4 + 2]; cv.w = colAcc[c * 4 + 3];
        cp[c * 256 + tid] = cv;
    }
}

// K3a: reduce col partials -> cs.  Grid (12, P), 256 thr; coalesced reads.
__global__ __launch_bounds__(256) void k3a_red(float* __restrict__ ws) {
    int p = blockIdx.y;
    int col = blockIdx.x * 256 + threadIdx.x;
    const float* cp = ws + CP_OFF + (size_t)p * KB2 * NN + col;
    float s = 0.f;
#pragma unroll 4
    for (int b = 0; b < KB2; ++b) s += cp[(size_t)b * NN];
    ws[CS_OFF + p * NN + col] = s;
}

// K3b: per-p scalars. lamb = max(max rs, max cs); r = N*lamb - T.
// Analytic: tt col-0 sum == lamb, so denom = lamb.
// u_i = (lamb-rs_i)/(r*lamb); v_j = lamb-cs_j; att = e>0 ? e/lamb + u_i*v_j : e
__global__ __launch_bounds__(256) void k3b_scal(float* __restrict__ ws) {
    int p = blockIdx.x;
    int tid = threadIdx.x;
    const float* rs = ws + RS_OFF + p * NN;
    const float* cs = ws + CS_OFF + p * NN;
    float mx = -3.4e38f, sum = 0.f;
    for (int i = tid; i < NN; i += 256) {
        float rv = rs[i], cv = cs[i];
        mx = fmaxf(mx, fmaxf(rv, cv));
        sum += rv;
    }
#pragma unroll
    for (int off = 32; off > 0; off >>= 1) {
        mx = fmaxf(mx, __shfl_down(mx, off));
        sum += __shfl_down(sum, off);
    }
    __shared__ float smx[4], ssum[4];
    __shared__ float s_lamb, s_invlr;
    if ((tid & 63) == 0) { smx[tid >> 6] = mx; ssum[tid >> 6] = sum; }
    __syncthreads();
    if (tid == 0) {
        float lamb = fmaxf(fmaxf(smx[0], smx[1]), fmaxf(smx[2], smx[3]));
        float T = ssum[0] + ssum[1] + ssum[2] + ssum[3];
        float r = (float)NN * lamb - T;
        s_lamb = lamb;
        s_invlr = 1.f / (r * lamb);
        ws[SCAL_OFF + p] = 1.f / lamb;
    }
    __syncthreads();
    float lamb = s_lamb, invlr = s_invlr;
    for (int i = tid; i < NN; i += 256) {
        ws[U_OFF + p * NN + i] = (lamb - rs[i]) * invlr;
        ws[V_OFF + p * NN + i] = lamb - cs[i];
    }
}

// K4: h_prime = att(e) @ Wh via bf16 MFMA; out0[i, p*64+f] = elu.
// 1 wave per block, 16 rows, K-tile 32. Grid (192, P) = 768 blocks (3/CU).
// A staged via att transform -> bf16 LDS [16][56] (112B rows: 16B-aligned, 2-way banks).
// B staged from WhT bf16 -> LDS [64][56]. Registered prefetch of next K-tile.
__global__ __launch_bounds__(64) void k4_mfma(const float* __restrict__ e_in,
                                              const float* __restrict__ ws,
                                              float* __restrict__ out0) {
    int p = blockIdx.y;
    int row0 = blockIdx.x * 16;
    int tid = threadIdx.x;
    __shared__ __align__(16) unsigned short sA[16][56];
    __shared__ __align__(16) unsigned short sB[64][56];
    const unsigned short* whT = (const unsigned short*)(ws + WHT_OFF);
    const float* u = ws + U_OFF + p * NN;
    const float* v = ws + V_OFF + p * NN;
    float invl = ws[SCAL_OFF + p];
    const float* eslice = e_in + (size_t)p * NN * NN;

    int arow = tid >> 2;          // staging row 0..15
    int kg = tid & 3;             // staging k-group (8 floats)
    float u_r = u[row0 + arow];
    const float4* erow = (const float4*)(eslice + (size_t)(row0 + arow) * NN);
    const float4* vrow = (const float4*)v;
    const int4* wrow = (const int4*)(whT + (size_t)tid * NN);  // B row f = tid

    floatx4 acc[4];
#pragma unroll
    for (int nt = 0; nt < 4; ++nt)
#pragma unroll
        for (int i = 0; i < 4; ++i) acc[nt][i] = 0.f;

    float4 e0, e1, v0, v1;
    int4 b0, b1, b2, b3;
    auto ldg = [&](int k0) {
        int idx = (k0 >> 2) + kg * 2;
        e0 = erow[idx]; e1 = erow[idx + 1];
        v0 = vrow[idx]; v1 = vrow[idx + 1];
        int widx = k0 >> 3;       // int4 = 8 shorts
        b0 = wrow[widx]; b1 = wrow[widx + 1]; b2 = wrow[widx + 2]; b3 = wrow[widx + 3];
    };
    ldg(0);
    for (int k0 = 0; k0 < NN; k0 += 32) {
        float a0 = e0.x > 0.f ? fmaf(u_r, v0.x, e0.x * invl) : e0.x;
        float a1 = e0.y > 0.f ? fmaf(u_r, v0.y, e0.y * invl) : e0.y;
        float a2 = e0.z > 0.f ? fmaf(u_r, v0.z, e0.z * invl) : e0.z;
        float a3 = e0.w > 0.f ? fmaf(u_r, v0.w, e0.w * invl) : e0.w;
        float a4 = e1.x > 0.f ? fmaf(u_r, v1.x, e1.x * invl) : e1.x;
        float a5 = e1.y > 0.f ? fmaf(u_r, v1.y, e1.y * invl) : e1.y;
        float a6 = e1.z > 0.f ? fmaf(u_r, v1.z, e1.z * invl) : e1.z;
        float a7 = e1.w > 0.f ? fmaf(u_r, v1.w, e1.w * invl) : e1.w;
        int4 pa;
        pa.x = (int)f2bf(a0) | ((int)f2bf(a1) << 16);
        pa.y = (int)f2bf(a2) | ((int)f2bf(a3) << 16);
        pa.z = (int)f2bf(a4) | ((int)f2bf(a5) << 16);
        pa.w = (int)f2bf(a6) | ((int)f2bf(a7) << 16);
        *(int4*)&sA[arow][kg * 8] = pa;
        *(int4*)&sB[tid][0]  = b0;
        *(int4*)&sB[tid][8]  = b1;
        *(int4*)&sB[tid][16] = b2;
        *(int4*)&sB[tid][24] = b3;
        __syncthreads();
        if (k0 + 32 < NN) ldg(k0 + 32);   // prefetch next tile while MFMAs run
        int mrow = tid & 15;
        int kq = tid >> 4;
        short8 af = *(const short8*)&sA[mrow][kq * 8];
#pragma unroll
        for (int nt = 0; nt < 4; ++nt) {
            short8 bf = *(const short8*)&sB[nt * 16 + mrow][kq * 8];
            acc[nt] = __builtin_amdgcn_mfma_f32_16x16x32_bf16(af, bf, acc[nt], 0, 0, 0);
        }
        __syncthreads();
    }
    // D layout: col = lane&15, row = (lane>>4)*4 + reg  [m89-verified]
#pragma unroll
    for (int nt = 0; nt < 4; ++nt)
#pragma unroll
        for (int r = 0; r < 4; ++r) {
            float x = acc[nt][r];
            x = x > 0.f ? x : (expf(x) - 1.0f);   // elu alpha=1
            int orow = row0 + (tid >> 4) * 4 + r;
            out0[(size_t)orow * (PP * FF) + p * FF + nt * 16 + (tid & 15)] = x;
        }
}

extern "C" void kernel_launch(void* const* d_in, const int* in_sizes, int n_in,
                              void* d_out, int out_size, void* d_ws, size_t ws_size,
                              hipStream_t stream) {
    const float* h    = (const float*)d_in[0];
    const float* edge = (const float*)d_in[1];
    const float* W    = (const float*)d_in[2];
    const float* a    = (const float*)d_in[3];
    float* out0  = (float*)d_out;                // [N, P*F] elu output
    float* e_out = out0 + (size_t)NN * PP * FF;  // [P, N, N] e output
    float* ws = (float*)d_ws;

    k1_gemm<<<NN, 64, 0, stream>>>(h, W, a, ws);
    k2_e<<<dim3(NN / 32, PP), 256, 0, stream>>>(edge, e_out, ws);
    k3a_red<<<dim3(NN / 256, PP), 256, 0, stream>>>(ws);
    k3b_scal<<<PP, 256, 0, stream>>>(ws);
    k4_mfma<<<dim3(NN / 16, PP), 64, 0, stream>>>(e_out, ws, out0);
}

// Round 3
// 394.860 us; speedup vs baseline: 1.2712x; 1.0116x over previous
//
#include <hip/hip_runtime.h>
#include <math.h>

#define NN 3072
#define PP 4
#define INF_ 256
#define FF 64
#define LEAK 0.2f
#define KB2 384            // k2 blocks per p (8 rows each)
#define KS 4               // k4 K-split factor
#define KCH (NN / KS)      // 768 K per chunk
#define PNF (PP * NN * FF) // 786432

// workspace layout (float offsets)
#define WH1_OFF  0                         // 3072
#define WH2_OFF  (WH1_OFF + NN)
#define RS_OFF   (WH2_OFF + NN)            // P*N
#define CS_OFF   (RS_OFF + PP * NN)        // P*N
#define U_OFF    (CS_OFF + PP * NN)        // P*N
#define V_OFF    (U_OFF + PP * NN)         // P*N
#define SCAL_OFF (V_OFF + PP * NN)         // 4 (+pad)
#define WHT_OFF  (SCAL_OFF + 8)            // bf16 WhT [F][N]: N*F/2 floats
#define CP_OFF   (WHT_OFF + (NN * FF) / 2) // col partials P*KB2*N floats (18.9MB);
                                           // reused by k4 as partial buffer (12.6MB)

typedef short short8 __attribute__((ext_vector_type(8)));
typedef float floatx4 __attribute__((ext_vector_type(4)));

__device__ inline unsigned short f2bf(float x) {
    unsigned u = __float_as_uint(x);
    return (unsigned short)((u + 0x7FFFu + ((u >> 16) & 1u)) >> 16);
}

// K1: Wh = h@W; store WhT bf16 [f][row]; Wh1 = Wh@a[:64]; Wh2 = Wh@a[64:]
__global__ __launch_bounds__(64) void k1_gemm(const float* __restrict__ h,
                                              const float* __restrict__ W,
                                              const float* __restrict__ a,
                                              float* __restrict__ ws) {
    int row = blockIdx.x;
    int f = threadIdx.x;
    __shared__ float hrow[INF_];
    ((float4*)hrow)[f] = ((const float4*)(h + (size_t)row * INF_))[f];
    __syncthreads();
    float acc = 0.f;
#pragma unroll 8
    for (int k = 0; k < INF_; ++k) acc = fmaf(hrow[k], W[k * FF + f], acc);
    unsigned short* whT = (unsigned short*)(ws + WHT_OFF);
    whT[(size_t)f * NN + row] = f2bf(acc);
    float s1 = acc * a[f];
    float s2 = acc * a[FF + f];
#pragma unroll
    for (int off = 32; off > 0; off >>= 1) {
        s1 += __shfl_down(s1, off);
        s2 += __shfl_down(s2, off);
    }
    if (f == 0) { ws[WH1_OFF + row] = s1; ws[WH2_OFF + row] = s2; }
}

// K2: e = leaky(Wh1[i]+Wh2[j])*edge; write e; row sums direct; col partials.
// 8 rows x 3072 cols per block. Grid (384, P) = 1536 blocks -> 24 waves/CU.
__global__ __launch_bounds__(256) void k2_e(const float* __restrict__ edge,
                                            float* __restrict__ e_out,
                                            float* __restrict__ ws) {
    int p = blockIdx.y;
    int row0 = blockIdx.x * 8;
    int tid = threadIdx.x;
    const float* Wh1 = ws + WH1_OFF;
    const float4* Wh2v = (const float4*)(ws + WH2_OFF);
    float4 wv[3];
#pragma unroll
    for (int c = 0; c < 3; ++c) wv[c] = Wh2v[c * 256 + tid];
    float colAcc[12];
#pragma unroll
    for (int i = 0; i < 12; ++i) colAcc[i] = 0.f;
    __shared__ float rowpart[8][4];
    const size_t slice = (size_t)p * NN * NN;
#pragma unroll 2
    for (int r = 0; r < 8; ++r) {
        int row = row0 + r;
        float w1 = Wh1[row];
        const float4* ein = (const float4*)(edge + slice + (size_t)row * NN);
        float4* eout = (float4*)(e_out + slice + (size_t)row * NN);
        float racc = 0.f;
#pragma unroll
        for (int c = 0; c < 3; ++c) {
            int j4 = c * 256 + tid;
            float4 ea = ein[j4];
            float4 w = wv[c];
            float4 ev;
            float b;
            b = w1 + w.x; b = b > 0.f ? b : LEAK * b; ev.x = b * ea.x;
            b = w1 + w.y; b = b > 0.f ? b : LEAK * b; ev.y = b * ea.y;
            b = w1 + w.z; b = b > 0.f ? b : LEAK * b; ev.z = b * ea.z;
            b = w1 + w.w; b = b > 0.f ? b : LEAK * b; ev.w = b * ea.w;
            eout[j4] = ev;
            colAcc[c * 4 + 0] += ev.x; colAcc[c * 4 + 1] += ev.y;
            colAcc[c * 4 + 2] += ev.z; colAcc[c * 4 + 3] += ev.w;
            racc += (ev.x + ev.y) + (ev.z + ev.w);
        }
#pragma unroll
        for (int off = 32; off > 0; off >>= 1) racc += __shfl_down(racc, off);
        if ((tid & 63) == 0) rowpart[r][tid >> 6] = racc;
    }
    __syncthreads();
    if (tid < 32) {
        float vv = rowpart[tid >> 2][tid & 3];
        vv += __shfl_down(vv, 2);
        vv += __shfl_down(vv, 1);
        if ((tid & 3) == 0) ws[RS_OFF + p * NN + row0 + (tid >> 2)] = vv;
    }
    float4* cp = (float4*)(ws + CP_OFF + (size_t)(p * KB2 + blockIdx.x) * NN);
#pragma unroll
    for (int c = 0; c < 3; ++c) {
        float4 cv;
        cv.x = colAcc[c * 4 + 0]; cv.y = colAcc[c * 4 + 1];
        cv.z = colAcc[c * 4 + 2]; cv.w = colAcc[c * 4 + 3];
        cp[c * 256 + tid] = cv;
    }
}

// K3a: reduce 384 col partials -> cs. Grid (48, P); 256 thr = 64 cols x 4 chunks.
__global__ __launch_bounds__(256) void k3a_red(float* __restrict__ ws) {
    int p = blockIdx.y;
    int col = blockIdx.x * 64 + (threadIdx.x & 63);
    int chunk = threadIdx.x >> 6;  // 0..3, 96 partials each
    const float* cp = ws + CP_OFF + (size_t)p * KB2 * NN + (size_t)chunk * 96 * NN + col;
    float s = 0.f;
#pragma unroll 8
    for (int b = 0; b < 96; ++b) s += cp[(size_t)b * NN];
    __shared__ float sred[4][64];
    sred[chunk][threadIdx.x & 63] = s;
    __syncthreads();
    if (threadIdx.x < 64) {
        float t = sred[0][threadIdx.x] + sred[1][threadIdx.x] +
                  sred[2][threadIdx.x] + sred[3][threadIdx.x];
        ws[CS_OFF + p * NN + col] = t;
    }
}

// K3b: per-p scalars. lamb = max(max rs, max cs); r = N*lamb - T.
// Analytic: tt col-0 sum == lamb => denom = lamb.
// u_i = (lamb-rs_i)/(r*lamb); v_j = lamb-cs_j; att = e>0 ? e/lamb + u_i*v_j : e
__global__ __launch_bounds__(256) void k3b_scal(float* __restrict__ ws) {
    int p = blockIdx.x;
    int tid = threadIdx.x;
    const float* rs = ws + RS_OFF + p * NN;
    const float* cs = ws + CS_OFF + p * NN;
    float mx = -3.4e38f, sum = 0.f;
    for (int i = tid; i < NN; i += 256) {
        float rv = rs[i], cv = cs[i];
        mx = fmaxf(mx, fmaxf(rv, cv));
        sum += rv;
    }
#pragma unroll
    for (int off = 32; off > 0; off >>= 1) {
        mx = fmaxf(mx, __shfl_down(mx, off));
        sum += __shfl_down(sum, off);
    }
    __shared__ float smx[4], ssum[4];
    __shared__ float s_lamb, s_invlr;
    if ((tid & 63) == 0) { smx[tid >> 6] = mx; ssum[tid >> 6] = sum; }
    __syncthreads();
    if (tid == 0) {
        float lamb = fmaxf(fmaxf(smx[0], smx[1]), fmaxf(smx[2], smx[3]));
        float T = ssum[0] + ssum[1] + ssum[2] + ssum[3];
        float r = (float)NN * lamb - T;
        s_lamb = lamb;
        s_invlr = 1.f / (r * lamb);
        ws[SCAL_OFF + p] = 1.f / lamb;
    }
    __syncthreads();
    float lamb = s_lamb, invlr = s_invlr;
    for (int i = tid; i < NN; i += 256) {
        ws[U_OFF + p * NN + i] = (lamb - rs[i]) * invlr;
        ws[V_OFF + p * NN + i] = lamb - cs[i];
    }
}

// K4: partial h_prime = att(e[:, Kchunk]) @ Wh[Kchunk, :] via bf16 MFMA.
// Grid (192, P, KS) = 3072 single-wave blocks -> 12 waves/CU.
// Partial [16x64] f32 per block into ws (cp region reused), layout [z][p][n][f].
__global__ __launch_bounds__(64) void k4_mfma(const float* __restrict__ e_in,
                                              float* __restrict__ ws) {
    int p = blockIdx.y;
    int z = blockIdx.z;
    int row0 = blockIdx.x * 16;
    int tid = threadIdx.x;
    __shared__ __align__(16) unsigned short sA[16][56];
    __shared__ __align__(16) unsigned short sB[64][56];
    const unsigned short* whT = (const unsigned short*)(ws + WHT_OFF);
    const float* u = ws + U_OFF + p * NN;
    const float* v = ws + V_OFF + p * NN;
    float invl = ws[SCAL_OFF + p];
    const float* eslice = e_in + (size_t)p * NN * NN;

    int arow = tid >> 2;          // staging row 0..15
    int kg = tid & 3;             // staging k-group (8 floats)
    float u_r = u[row0 + arow];
    const float4* erow = (const float4*)(eslice + (size_t)(row0 + arow) * NN);
    const float4* vrow = (const float4*)v;
    const int4* wrow = (const int4*)(whT + (size_t)tid * NN);  // B row f = tid

    floatx4 acc[4];
#pragma unroll
    for (int nt = 0; nt < 4; ++nt)
#pragma unroll
        for (int i = 0; i < 4; ++i) acc[nt][i] = 0.f;

    const int kbase = z * KCH;
    float4 e0, e1, v0, v1;
    int4 b0, b1, b2, b3;
    auto ldg = [&](int k0) {
        int idx = (k0 >> 2) + kg * 2;
        e0 = erow[idx]; e1 = erow[idx + 1];
        v0 = vrow[idx]; v1 = vrow[idx + 1];
        int widx = k0 >> 3;
        b0 = wrow[widx]; b1 = wrow[widx + 1]; b2 = wrow[widx + 2]; b3 = wrow[widx + 3];
    };
    ldg(kbase);
    for (int k0 = kbase; k0 < kbase + KCH; k0 += 32) {
        float a0 = e0.x > 0.f ? fmaf(u_r, v0.x, e0.x * invl) : e0.x;
        float a1 = e0.y > 0.f ? fmaf(u_r, v0.y, e0.y * invl) : e0.y;
        float a2 = e0.z > 0.f ? fmaf(u_r, v0.z, e0.z * invl) : e0.z;
        float a3 = e0.w > 0.f ? fmaf(u_r, v0.w, e0.w * invl) : e0.w;
        float a4 = e1.x > 0.f ? fmaf(u_r, v1.x, e1.x * invl) : e1.x;
        float a5 = e1.y > 0.f ? fmaf(u_r, v1.y, e1.y * invl) : e1.y;
        float a6 = e1.z > 0.f ? fmaf(u_r, v1.z, e1.z * invl) : e1.z;
        float a7 = e1.w > 0.f ? fmaf(u_r, v1.w, e1.w * invl) : e1.w;
        int4 pa;
        pa.x = (int)f2bf(a0) | ((int)f2bf(a1) << 16);
        pa.y = (int)f2bf(a2) | ((int)f2bf(a3) << 16);
        pa.z = (int)f2bf(a4) | ((int)f2bf(a5) << 16);
        pa.w = (int)f2bf(a6) | ((int)f2bf(a7) << 16);
        *(int4*)&sA[arow][kg * 8] = pa;
        *(int4*)&sB[tid][0]  = b0;
        *(int4*)&sB[tid][8]  = b1;
        *(int4*)&sB[tid][16] = b2;
        *(int4*)&sB[tid][24] = b3;
        __syncthreads();
        if (k0 + 32 < kbase + KCH) ldg(k0 + 32);  // prefetch next K-tile
        int mrow = tid & 15;
        int kq = tid >> 4;
        short8 af = *(const short8*)&sA[mrow][kq * 8];
#pragma unroll
        for (int nt = 0; nt < 4; ++nt) {
            short8 bf = *(const short8*)&sB[nt * 16 + mrow][kq * 8];
            acc[nt] = __builtin_amdgcn_mfma_f32_16x16x32_bf16(af, bf, acc[nt], 0, 0, 0);
        }
        __syncthreads();
    }
    // D layout: col = lane&15, row = (lane>>4)*4 + reg  [m89-verified]
    float* part = ws + CP_OFF + (size_t)z * PNF + (size_t)p * NN * FF + (size_t)row0 * FF;
#pragma unroll
    for (int nt = 0; nt < 4; ++nt)
#pragma unroll
        for (int r = 0; r < 4; ++r)
            part[((tid >> 4) * 4 + r) * FF + nt * 16 + (tid & 15)] = acc[nt][r];
}

// K5: sum KS partials + elu -> out0[n, p*64+f]. Grid 3072 x 256.
__global__ __launch_bounds__(256) void k5_red(const float* __restrict__ ws,
                                              float* __restrict__ out0) {
    int i = blockIdx.x * 256 + threadIdx.x;  // over [p][n][f]
    const float* part = ws + CP_OFF;
    float s = part[i] + part[PNF + i] + part[2 * PNF + i] + part[3 * (size_t)PNF + i];
    s = s > 0.f ? s : (expf(s) - 1.0f);  // elu alpha=1
    int f = i & 63;
    int n = (i >> 6) & (NN - 1);
    int p = i >> 6 >> 11;  // i / (NN*FF) with NN*FF = 2^17... compute safely below
    p = i / (NN * FF);
    n = (i - p * NN * FF) >> 6;
    out0[(size_t)n * (PP * FF) + p * FF + f] = s;
}

extern "C" void kernel_launch(void* const* d_in, const int* in_sizes, int n_in,
                              void* d_out, int out_size, void* d_ws, size_t ws_size,
                              hipStream_t stream) {
    const float* h    = (const float*)d_in[0];
    const float* edge = (const float*)d_in[1];
    const float* W    = (const float*)d_in[2];
    const float* a    = (const float*)d_in[3];
    float* out0  = (float*)d_out;                // [N, P*F] elu output
    float* e_out = out0 + (size_t)NN * PP * FF;  // [P, N, N] e output
    float* ws = (float*)d_ws;

    k1_gemm<<<NN, 64, 0, stream>>>(h, W, a, ws);
    k2_e<<<dim3(NN / 8, PP), 256, 0, stream>>>(edge, e_out, ws);
    k3a_red<<<dim3(NN / 64, PP), 256, 0, stream>>>(ws);
    k3b_scal<<<PP, 256, 0, stream>>>(ws);
    k4_mfma<<<dim3(NN / 16, PP, KS), 64, 0, stream>>>(e_out, ws);
    k5_red<<<PNF / 256, 256, 0, stream>>>(ws, out0);
}